// Round 16
// baseline (1590.730 us; speedup 1.0000x reference)
//
#include <hip/hip_runtime.h>
#include <hip/hip_bf16.h>

// N_NODES=50000, N_EDGES=1600000, ATOM_F=64, FP_SIZE=2048, N_GRAPHS=2000
#define AF 64
#define NFP 2048
#define MAXG 4   // LDS-pooled graphs per 32-node block (fallback: global atomics)
#define LOG2E 1.4426950408889634f

typedef __attribute__((ext_vector_type(8))) short bf16x8;
typedef __attribute__((ext_vector_type(4))) float f32x4;

__device__ __forceinline__ ushort f2bf(float f) {
    unsigned u = __float_as_uint(f);
    return (ushort)((u + 0x7FFF + ((u >> 16) & 1)) >> 16);   // RNE
}
__device__ __forceinline__ float bf2f(ushort u) {
    return __uint_as_float((unsigned)u << 16);
}

// ---------------------------------------------------------------------------
// Generic histogram (int32 keys)
// ---------------------------------------------------------------------------
__global__ __launch_bounds__(256) void hist_kernel(
    const int* __restrict__ keys, int* __restrict__ counts, int n)
{
    int e = blockIdx.x * 256 + threadIdx.x;
    if (e < n) atomicAdd(&counts[keys[e]], 1);
}

// XCD-partitioned histogram
__global__ __launch_bounds__(256) void hist_part_kernel(
    const int* __restrict__ dst, int* __restrict__ counts,
    int n_edges, int npr, int nchunks)
{
    int r = blockIdx.x & 7;
    int c = blockIdx.x >> 3;
    int lo = r * npr, hi = lo + npr;
    int per = (n_edges + nchunks - 1) / nchunks;
    int e0 = c * per;
    int e1 = e0 + per; if (e1 > n_edges) e1 = n_edges;
    for (int e = e0 + (int)threadIdx.x; e < e1; e += 256) {
        int d = dst[e];
        if (d >= lo && d < hi) atomicAdd(&counts[d], 1);
    }
}

// single-block exclusive scan, in place; data[n] = total  (small arrays only)
__global__ __launch_bounds__(1024) void scan_kernel(int* data, int n)
{
    __shared__ int wsum[16];
    __shared__ int chunk_total;
    int t = threadIdx.x, lane = t & 63, w = t >> 6;
    int running = 0;
    for (int base = 0; base < n; base += 1024) {
        int i = base + t;
        int v = (i < n) ? data[i] : 0;
        int x = v;
        #pragma unroll
        for (int off = 1; off < 64; off <<= 1) {
            int y = __shfl_up(x, off);
            if (lane >= off) x += y;
        }
        if (lane == 63) wsum[w] = x;
        __syncthreads();
        if (t == 0) {
            int s = 0;
            #pragma unroll
            for (int q = 0; q < 16; ++q) { int tmp = wsum[q]; wsum[q] = s; s += tmp; }
            chunk_total = s;
        }
        __syncthreads();
        if (i < n) data[i] = x - v + wsum[w] + running;
        running += chunk_total;
        __syncthreads();
    }
    if (t == 0) data[n] = running;
}

// --- hierarchical scan for large arrays: block scan + sums scan + add ---
__global__ __launch_bounds__(1024) void scan_block_kernel(
    int* __restrict__ data, int* __restrict__ bsum, int n)
{
    __shared__ int wsum[16];
    int t = threadIdx.x, lane = t & 63, w = t >> 6;
    int i = blockIdx.x * 1024 + t;
    int v = (i < n) ? data[i] : 0;
    int x = v;
    #pragma unroll
    for (int off = 1; off < 64; off <<= 1) {
        int y = __shfl_up(x, off);
        if (lane >= off) x += y;
    }
    if (lane == 63) wsum[w] = x;
    __syncthreads();
    if (t == 0) {
        int s = 0;
        #pragma unroll
        for (int q = 0; q < 16; ++q) { int tmp = wsum[q]; wsum[q] = s; s += tmp; }
        bsum[blockIdx.x] = s;
    }
    __syncthreads();
    if (i < n) data[i] = x - v + wsum[w];
}

__global__ __launch_bounds__(1024) void scan_sums_kernel(int* bsum, int nb)
{
    __shared__ int wsum[16];
    int t = threadIdx.x, lane = t & 63, w = t >> 6;
    int v = (t < nb) ? bsum[t] : 0;
    int x = v;
    #pragma unroll
    for (int off = 1; off < 64; off <<= 1) {
        int y = __shfl_up(x, off);
        if (lane >= off) x += y;
    }
    if (lane == 63) wsum[w] = x;
    __syncthreads();
    if (t == 0) {
        int s = 0;
        #pragma unroll
        for (int q = 0; q < 16; ++q) { int tmp = wsum[q]; wsum[q] = s; s += tmp; }
        bsum[nb] = s;                      // total
    }
    __syncthreads();
    if (t < nb) bsum[t] = x - v + wsum[w];
}

__global__ __launch_bounds__(256) void scan_add_kernel(
    int* __restrict__ data, const int* __restrict__ bsum, int n, int nb)
{
    int i = blockIdx.x * 256 + threadIdx.x;
    if (i < n) data[i] += bsum[i >> 10];
    if (i == 0) data[n] = bsum[nb];
}

// XCD-partitioned id scatter
__global__ __launch_bounds__(256) void scatter_part_kernel(
    const int* __restrict__ src, const int* __restrict__ dst,
    int* __restrict__ cursor, int* __restrict__ esrc,
    int n_edges, int npr, int nchunks)
{
    int r = blockIdx.x & 7;
    int c = blockIdx.x >> 3;
    int lo = r * npr, hi = lo + npr;
    int per = (n_edges + nchunks - 1) / nchunks;
    int e0 = c * per;
    int e1 = e0 + per; if (e1 > n_edges) e1 = n_edges;
    for (int e = e0 + (int)threadIdx.x; e < e1; e += 256) {
        int d = dst[e];
        if (d >= lo && d < hi) {
            int pos = atomicAdd(&cursor[d], 1);
            esrc[pos] = src[e];
        }
    }
}

// ---------------------------------------------------------------------------
// fp32 -> bf16 convert with scale
// ---------------------------------------------------------------------------
__global__ __launch_bounds__(256) void f2bf_kernel(
    const float* __restrict__ W, ushort* __restrict__ Wbf, float scale, int n)
{
    int i = blockIdx.x * 256 + threadIdx.x;
    if (i < n) Wbf[i] = f2bf(W[i] * scale);
}

// ---------------------------------------------------------------------------
// Fused gather-aggregate (CSR, bf16 rows) + self-loop + 64x64 sigmoid MLP.
// (R14-proven version)
// ---------------------------------------------------------------------------
__global__ __launch_bounds__(256) void agg_mlp_kernel(
    const ushort* __restrict__ hbf, const int* __restrict__ offsets,
    const int* __restrict__ esrc, const float* __restrict__ Hw,
    const float* __restrict__ Hb, ushort* __restrict__ outbf, int n_nodes)
{
    __shared__ float Hw_s[AF * 65];
    __shared__ __align__(16) float part[4][8][AF];   // 8 KB
    __shared__ float a_red[4][AF];
    __shared__ float hb_s[AF];

    int t = threadIdx.x;
    for (int idx = t; idx < AF * AF; idx += 256) {
        int j = idx >> 6, k = idx & 63;
        Hw_s[j * 65 + k] = Hw[idx];
    }
    if (t < AF) hb_s[t] = Hb[t];

    int w = t >> 6, lane = t & 63;
    int sub = lane >> 3, f8 = lane & 7;
    int i = blockIdx.x * 4 + w;

    float acc[8] = {0.f, 0.f, 0.f, 0.f, 0.f, 0.f, 0.f, 0.f};
    if (i < n_nodes) {
        int o0 = offsets[i], o1 = offsets[i + 1];
        const int* ep = esrc + o0;
        int deg = o1 - o0;
        for (int j = 0; j < deg; j += 8) {
            int jj = j + sub;
            if (jj < deg) {
                int s = ep[jj];
                bf16x8 v = *(const bf16x8*)(hbf + (size_t)s * AF + f8 * 8);
                #pragma unroll
                for (int q = 0; q < 8; ++q) acc[q] += bf2f((ushort)v[q]);
            }
        }
    }
    *(float4*)&part[w][sub][f8 * 8]     = make_float4(acc[0], acc[1], acc[2], acc[3]);
    *(float4*)&part[w][sub][f8 * 8 + 4] = make_float4(acc[4], acc[5], acc[6], acc[7]);
    __syncthreads();

    if (i < n_nodes) {
        float val = bf2f(hbf[(size_t)i * AF + lane]);   // self loop
        #pragma unroll
        for (int s8 = 0; s8 < 8; ++s8) val += part[w][s8][lane];
        a_red[w][lane] = val;
    }
    __syncthreads();

    if (i < n_nodes) {
        float z = hb_s[lane];
        #pragma unroll
        for (int k = 0; k < AF; ++k)
            z = fmaf(a_red[w][k], Hw_s[lane * 65 + k], z);
        float sg = 1.f / (1.f + __expf(-z));
        outbf[(size_t)i * AF + lane] = f2bf(sg);
    }
}

// ---------------------------------------------------------------------------
// FUSED fingerprint: R14 structure, but pass-2 pooling via BRANCHLESS per-value
// LDS atomicAdd (no gi mask loop, no cross-lane shuffles on the hot path).
// rel>=MAXG values get scale 0 (add 0.0 to row 0, harmless); rare ng>MAXG
// blocks handle the excess graphs with the old masked+shfl global-atomic path.
// ---------------------------------------------------------------------------
__global__ __launch_bounds__(256) void fp_node_pool_kernel(
    const ushort* __restrict__ updbf, const ushort* __restrict__ Wbf,
    const float* __restrict__ Wb, const int* __restrict__ batch,
    float* __restrict__ partial, float* __restrict__ out, int n_nodes)
{
    __shared__ float red[4][32];
    __shared__ float sden_s[32];
    __shared__ int   bat_s[32];
    __shared__ __align__(16) float pacc[MAXG * NFP];   // 32 KB

    int t = threadIdx.x, wave = t >> 6, lane = t & 63;
    int G = lane >> 4, sl = lane & 15;
    int cw = wave * 512;
    int b = blockIdx.x;
    int i0 = b * 32;

    const ushort* wbase = Wbf + (size_t)(cw + sl) * AF + G * 8;

    // A fragments (updbf padded + zeroed past n_nodes)
    bf16x8 a00, a01, a10, a11;
    {
        const ushort* p0 = updbf + (size_t)(i0 + sl) * AF + G * 8;
        a00 = *(const bf16x8*)p0;
        a01 = *(const bf16x8*)(p0 + 32);
        const ushort* p1 = updbf + (size_t)(i0 + 16 + sl) * AF + G * 8;
        a10 = *(const bf16x8*)p1;
        a11 = *(const bf16x8*)(p1 + 32);
    }

    // ---- pass 1: denominators via exp2 (weights pre-scaled by log2e) ----
    float s0[4] = {0.f, 0.f, 0.f, 0.f};
    float s1[4] = {0.f, 0.f, 0.f, 0.f};
    {
        const ushort* wp0 = wbase;
        bf16x8 nb0 = *(const bf16x8*)wp0;
        bf16x8 nb1 = *(const bf16x8*)(wp0 + 32);
        #pragma unroll 4
        for (int ct = 0; ct < 32; ++ct) {
            bf16x8 b0 = nb0, b1 = nb1;
            if (ct < 31) {
                const ushort* wp = wbase + (size_t)((ct + 1) * 16) * AF;
                nb0 = *(const bf16x8*)wp;
                nb1 = *(const bf16x8*)(wp + 32);
            }
            float bias = Wb[cw + ct * 16 + sl] * LOG2E;
            f32x4 d0 = {0.f, 0.f, 0.f, 0.f};
            d0 = __builtin_amdgcn_mfma_f32_16x16x32_bf16(a00, b0, d0, 0, 0, 0);
            d0 = __builtin_amdgcn_mfma_f32_16x16x32_bf16(a01, b1, d0, 0, 0, 0);
            f32x4 d1 = {0.f, 0.f, 0.f, 0.f};
            d1 = __builtin_amdgcn_mfma_f32_16x16x32_bf16(a10, b0, d1, 0, 0, 0);
            d1 = __builtin_amdgcn_mfma_f32_16x16x32_bf16(a11, b1, d1, 0, 0, 0);
            #pragma unroll
            for (int r = 0; r < 4; ++r) {
                s0[r] += __builtin_amdgcn_exp2f(d0[r] + bias);
                s1[r] += __builtin_amdgcn_exp2f(d1[r] + bias);
            }
        }
    }
    #pragma unroll
    for (int mask = 1; mask <= 8; mask <<= 1) {
        #pragma unroll
        for (int r = 0; r < 4; ++r) {
            s0[r] += __shfl_xor(s0[r], mask);
            s1[r] += __shfl_xor(s1[r], mask);
        }
    }
    if (sl == 0) {
        #pragma unroll
        for (int r = 0; r < 4; ++r) {
            red[wave][G * 4 + r]      = s0[r];
            red[wave][16 + G * 4 + r] = s1[r];
        }
    }
    if (t < 32) {
        int n = i0 + t;
        bat_s[t] = batch[n < n_nodes ? n : (n_nodes - 1)];
    }
    __syncthreads();
    if (t < 32) {
        float s = red[0][t] + red[1][t] + red[2][t] + red[3][t];
        sden_s[t] = 1.f / s;
    }
    __syncthreads();

    int g_first = bat_s[0];
    int ng = bat_s[31] - g_first + 1;            // block-uniform
    int ngl = ng < MAXG ? ng : MAXG;

    // zero wave-local pacc slices (wave-exclusive cols: no barrier needed)
    for (int gi = 0; gi < ngl; ++gi) {
        *(float4*)&pacc[gi * NFP + cw + lane * 8]     = make_float4(0.f, 0.f, 0.f, 0.f);
        *(float4*)&pacc[gi * NFP + cw + lane * 8 + 4] = make_float4(0.f, 0.f, 0.f, 0.f);
    }

    // per-lane scales, graph ids, clamped LDS row bases
    float scL0[4], scL1[4];    // LDS path: 0 if invalid or rel>=MAXG
    float scO0[4], scO1[4];    // overflow path: plain sden (masked by gl later)
    int gl0[4], gl1[4];
    int rb0[4], rb1[4];
    #pragma unroll
    for (int r = 0; r < 4; ++r) {
        int l0 = G * 4 + r, l1 = l0 + 16;
        float sd0 = (i0 + l0 < n_nodes) ? sden_s[l0] : 0.f;
        float sd1 = (i0 + l1 < n_nodes) ? sden_s[l1] : 0.f;
        int r0 = bat_s[l0] - g_first;
        int r1 = bat_s[l1] - g_first;
        gl0[r] = bat_s[l0];
        gl1[r] = bat_s[l1];
        scO0[r] = sd0;
        scO1[r] = sd1;
        scL0[r] = (r0 < MAXG) ? sd0 : 0.f;
        scL1[r] = (r1 < MAXG) ? sd1 : 0.f;
        rb0[r] = ((r0 < MAXG) ? r0 : 0) * NFP;
        rb1[r] = ((r1 < MAXG) ? r1 : 0) * NFP;
    }

    // ---- pass 2: recompute tiles, branchless per-value LDS-atomic pool ----
    {
        const ushort* wp0 = wbase;
        bf16x8 nb0 = *(const bf16x8*)wp0;
        bf16x8 nb1 = *(const bf16x8*)(wp0 + 32);
        #pragma unroll 4
        for (int ct = 0; ct < 32; ++ct) {
            bf16x8 b0 = nb0, b1 = nb1;
            if (ct < 31) {
                const ushort* wp = wbase + (size_t)((ct + 1) * 16) * AF;
                nb0 = *(const bf16x8*)wp;
                nb1 = *(const bf16x8*)(wp + 32);
            }
            int col = cw + ct * 16 + sl;
            float bias = Wb[col] * LOG2E;
            f32x4 d0 = {0.f, 0.f, 0.f, 0.f};
            d0 = __builtin_amdgcn_mfma_f32_16x16x32_bf16(a00, b0, d0, 0, 0, 0);
            d0 = __builtin_amdgcn_mfma_f32_16x16x32_bf16(a01, b1, d0, 0, 0, 0);
            f32x4 d1 = {0.f, 0.f, 0.f, 0.f};
            d1 = __builtin_amdgcn_mfma_f32_16x16x32_bf16(a10, b0, d1, 0, 0, 0);
            d1 = __builtin_amdgcn_mfma_f32_16x16x32_bf16(a11, b1, d1, 0, 0, 0);
            float er0[4], er1[4];
            #pragma unroll
            for (int r = 0; r < 4; ++r) {
                er0[r] = __builtin_amdgcn_exp2f(d0[r] + bias);
                er1[r] = __builtin_amdgcn_exp2f(d1[r] + bias);
            }
            #pragma unroll
            for (int r = 0; r < 4; ++r) {
                atomicAdd(&pacc[rb0[r] + col], er0[r] * scL0[r]);
                atomicAdd(&pacc[rb1[r] + col], er1[r] * scL1[r]);
            }
            if (ng > MAXG) {                       // rare, block-uniform
                for (int gi = MAXG; gi < ng; ++gi) {
                    int g = g_first + gi;
                    float c = 0.f;
                    #pragma unroll
                    for (int r = 0; r < 4; ++r) {
                        c += (gl0[r] == g) ? er0[r] * scO0[r] : 0.f;
                        c += (gl1[r] == g) ? er1[r] * scO1[r] : 0.f;
                    }
                    c += __shfl_xor(c, 16);
                    c += __shfl_xor(c, 32);
                    if (G == 0)
                        unsafeAtomicAdd(&out[(size_t)g * NFP + col], c);
                }
            }
        }
    }

    // epilogue: plain-store partial rows (row = b + g, injective staircase)
    for (int gi = 0; gi < ng; ++gi) {
        float* row = partial + (size_t)(b + g_first + gi) * NFP;
        if (gi < MAXG) {
            *(float4*)&row[cw + lane * 8]     = *(float4*)&pacc[gi * NFP + cw + lane * 8];
            *(float4*)&row[cw + lane * 8 + 4] = *(float4*)&pacc[gi * NFP + cw + lane * 8 + 4];
        } else {
            *(float4*)&row[cw + lane * 8]     = make_float4(0.f, 0.f, 0.f, 0.f);
            *(float4*)&row[cw + lane * 8 + 4] = make_float4(0.f, 0.f, 0.f, 0.f);
        }
    }
}

// ---------------------------------------------------------------------------
// Per-graph reduce: out[g] += sum over covering 32-node blocks of partial[b+g].
// ---------------------------------------------------------------------------
__global__ __launch_bounds__(256) void fp_reduce_kernel(
    const float* __restrict__ partial, const int* __restrict__ goff,
    float* __restrict__ out)
{
    int g = blockIdx.x, t = threadIdx.x;
    int gs = goff[g], ge = goff[g + 1];
    if (ge <= gs) return;
    int b0 = gs >> 5, b1 = (ge - 1) >> 5;
    float4 acc0 = make_float4(0.f, 0.f, 0.f, 0.f);
    float4 acc1 = make_float4(0.f, 0.f, 0.f, 0.f);
    for (int b = b0; b <= b1; ++b) {
        const float* row = partial + (size_t)(b + g) * NFP;
        float4 v0 = *(const float4*)&row[t * 8];
        float4 v1 = *(const float4*)&row[t * 8 + 4];
        acc0.x += v0.x; acc0.y += v0.y; acc0.z += v0.z; acc0.w += v0.w;
        acc1.x += v1.x; acc1.y += v1.y; acc1.z += v1.z; acc1.w += v1.w;
    }
    float* po = &out[(size_t)g * NFP];
    float4 o0 = *(float4*)&po[t * 8];
    float4 o1 = *(float4*)&po[t * 8 + 4];
    o0.x += acc0.x; o0.y += acc0.y; o0.z += acc0.z; o0.w += acc0.w;
    o1.x += acc1.x; o1.y += acc1.y; o1.z += acc1.z; o1.w += acc1.w;
    *(float4*)&po[t * 8]     = o0;
    *(float4*)&po[t * 8 + 4] = o1;
}

// ---------------------------------------------------------------------------
extern "C" void kernel_launch(void* const* d_in, const int* in_sizes, int n_in,
                              void* d_out, int out_size, void* d_ws, size_t ws_size,
                              hipStream_t stream)
{
    const float* x    = (const float*)d_in[0];
    const float* H1_w = (const float*)d_in[1];
    const float* H1_b = (const float*)d_in[2];
    const float* W1_w = (const float*)d_in[3];
    const float* W1_b = (const float*)d_in[4];
    const float* H2_w = (const float*)d_in[5];
    const float* H2_b = (const float*)d_in[6];
    const float* W2_w = (const float*)d_in[7];
    const float* W2_b = (const float*)d_in[8];
    const int*   ei   = (const int*)d_in[9];
    const int*   batch= (const int*)d_in[10];

    const int n_nodes  = in_sizes[0] / AF;   // 50000
    const int n_edges  = in_sizes[9] / 2;    // 1600000
    const int n_graphs = out_size / NFP;     // 2000
    const int npad     = ((n_nodes + 127) / 128) * 128;   // 50048
    const int* src = ei;
    const int* dst = ei + n_edges;
    float* out = (float*)d_out;

    const int fp_blocks = (n_nodes + 31) / 32;            // 1563
    const int npairs    = fp_blocks + n_graphs + 1;       // partial rows
    const int nsb       = (n_nodes + 1023) / 1024;        // scan blocks (49)

    // workspace layout
    ushort* xbf     = (ushort*)d_ws;                     // npad*64
    ushort* ubf1    = xbf  + (size_t)npad * AF;          // npad*64
    ushort* ubf2    = ubf1 + (size_t)npad * AF;          // npad*64
    ushort* Wbf1    = ubf2 + (size_t)npad * AF;          // 131072
    ushort* Wbf2    = Wbf1 + (size_t)NFP * AF;           // 131072
    float*  partial = (float*)(Wbf2 + (size_t)NFP * AF); // npairs*NFP
    int*    offsets = (int*)(partial + (size_t)npairs * NFP);  // n_nodes+1
    int*    cursor  = offsets + (n_nodes + 1);           // n_nodes+1
    int*    goff    = cursor + (n_nodes + 1);            // n_graphs+1
    int*    bscan   = goff + (n_graphs + 1);             // nsb+1
    int*    esrc    = bscan + (nsb + 1);                 // n_edges

    const int nb = (n_nodes + 255) / 256;
    const int mlp_blocks = (n_nodes + 3) / 4;
    const int wn = NFP * AF;                 // 131072
    const int xn = n_nodes * AF;             // 3.2M
    const int npr = (n_nodes + 7) / 8;       // nodes per XCD-range
    const int nchunks = 256;                 // edge chunks per range sweep

    // --- one-time per launch: bf16 tables + CSR + graph offsets + pads ---
    f2bf_kernel<<<(xn + 255) / 256, 256, 0, stream>>>(x, xbf, 1.0f, xn);
    f2bf_kernel<<<(wn + 255) / 256, 256, 0, stream>>>(W1_w, Wbf1, LOG2E, wn);
    f2bf_kernel<<<(wn + 255) / 256, 256, 0, stream>>>(W2_w, Wbf2, LOG2E, wn);
    hipMemsetAsync(out, 0, (size_t)out_size * sizeof(float), stream);
    hipMemsetAsync(xbf + (size_t)n_nodes * AF, 0,
                   (size_t)(npad - n_nodes) * AF * sizeof(ushort), stream);
    hipMemsetAsync(ubf1 + (size_t)n_nodes * AF, 0,
                   (size_t)(npad - n_nodes) * AF * sizeof(ushort), stream);
    hipMemsetAsync(ubf2 + (size_t)n_nodes * AF, 0,
                   (size_t)(npad - n_nodes) * AF * sizeof(ushort), stream);
    hipMemsetAsync(offsets, 0, (size_t)(n_nodes + 1) * sizeof(int), stream);
    hipMemsetAsync(goff, 0, (size_t)(n_graphs + 1) * sizeof(int), stream);
    hist_part_kernel<<<nchunks * 8, 256, 0, stream>>>(dst, offsets, n_edges, npr, nchunks);
    hist_kernel<<<nb, 256, 0, stream>>>(batch, goff, n_nodes);
    scan_block_kernel<<<nsb, 1024, 0, stream>>>(offsets, bscan, n_nodes);
    scan_sums_kernel<<<1, 1024, 0, stream>>>(bscan, nsb);
    scan_add_kernel<<<(n_nodes + 255) / 256, 256, 0, stream>>>(offsets, bscan,
                                                               n_nodes, nsb);
    scan_kernel<<<1, 1024, 0, stream>>>(goff, n_graphs);
    hipMemcpyAsync(cursor, offsets, (size_t)n_nodes * sizeof(int),
                   hipMemcpyDeviceToDevice, stream);
    scatter_part_kernel<<<nchunks * 8, 256, 0, stream>>>(src, dst, cursor, esrc,
                                                         n_edges, npr, nchunks);

    // --- layer 1 ---
    agg_mlp_kernel<<<mlp_blocks, 256, 0, stream>>>(xbf, offsets, esrc,
                                                   H1_w, H1_b, ubf1, n_nodes);
    fp_node_pool_kernel<<<fp_blocks, 256, 0, stream>>>(ubf1, Wbf1, W1_b, batch,
                                                       partial, out, n_nodes);
    fp_reduce_kernel<<<n_graphs, 256, 0, stream>>>(partial, goff, out);

    // --- layer 2 ---
    agg_mlp_kernel<<<mlp_blocks, 256, 0, stream>>>(ubf1, offsets, esrc,
                                                   H2_w, H2_b, ubf2, n_nodes);
    fp_node_pool_kernel<<<fp_blocks, 256, 0, stream>>>(ubf2, Wbf2, W2_b, batch,
                                                       partial, out, n_nodes);
    fp_reduce_kernel<<<n_graphs, 256, 0, stream>>>(partial, goff, out);
}

// Round 17
// 595.247 us; speedup vs baseline: 2.6724x; 2.6724x over previous
//
#include <hip/hip_runtime.h>
#include <hip/hip_bf16.h>

// N_NODES=50000, N_EDGES=1600000, ATOM_F=64, FP_SIZE=2048, N_GRAPHS=2000
#define AF 64
#define NFP 2048
#define MAXG 3   // LDS-pooled graphs per 32-node block (fallback: global atomics)
#define LOG2E 1.4426950408889634f

typedef __attribute__((ext_vector_type(8))) short bf16x8;
typedef __attribute__((ext_vector_type(4))) float f32x4;

__device__ __forceinline__ ushort f2bf(float f) {
    unsigned u = __float_as_uint(f);
    return (ushort)((u + 0x7FFF + ((u >> 16) & 1)) >> 16);   // RNE
}
__device__ __forceinline__ float bf2f(ushort u) {
    return __uint_as_float((unsigned)u << 16);
}

// ---------------------------------------------------------------------------
// Generic histogram (int32 keys)
// ---------------------------------------------------------------------------
__global__ __launch_bounds__(256) void hist_kernel(
    const int* __restrict__ keys, int* __restrict__ counts, int n)
{
    int e = blockIdx.x * 256 + threadIdx.x;
    if (e < n) atomicAdd(&counts[keys[e]], 1);
}

// XCD-partitioned histogram
__global__ __launch_bounds__(256) void hist_part_kernel(
    const int* __restrict__ dst, int* __restrict__ counts,
    int n_edges, int npr, int nchunks)
{
    int r = blockIdx.x & 7;
    int c = blockIdx.x >> 3;
    int lo = r * npr, hi = lo + npr;
    int per = (n_edges + nchunks - 1) / nchunks;
    int e0 = c * per;
    int e1 = e0 + per; if (e1 > n_edges) e1 = n_edges;
    for (int e = e0 + (int)threadIdx.x; e < e1; e += 256) {
        int d = dst[e];
        if (d >= lo && d < hi) atomicAdd(&counts[d], 1);
    }
}

// single-block exclusive scan, in place; data[n] = total  (small arrays only)
__global__ __launch_bounds__(1024) void scan_kernel(int* data, int n)
{
    __shared__ int wsum[16];
    __shared__ int chunk_total;
    int t = threadIdx.x, lane = t & 63, w = t >> 6;
    int running = 0;
    for (int base = 0; base < n; base += 1024) {
        int i = base + t;
        int v = (i < n) ? data[i] : 0;
        int x = v;
        #pragma unroll
        for (int off = 1; off < 64; off <<= 1) {
            int y = __shfl_up(x, off);
            if (lane >= off) x += y;
        }
        if (lane == 63) wsum[w] = x;
        __syncthreads();
        if (t == 0) {
            int s = 0;
            #pragma unroll
            for (int q = 0; q < 16; ++q) { int tmp = wsum[q]; wsum[q] = s; s += tmp; }
            chunk_total = s;
        }
        __syncthreads();
        if (i < n) data[i] = x - v + wsum[w] + running;
        running += chunk_total;
        __syncthreads();
    }
    if (t == 0) data[n] = running;
}

// --- hierarchical scan for large arrays: block scan + sums scan + add ---
__global__ __launch_bounds__(1024) void scan_block_kernel(
    int* __restrict__ data, int* __restrict__ bsum, int n)
{
    __shared__ int wsum[16];
    int t = threadIdx.x, lane = t & 63, w = t >> 6;
    int i = blockIdx.x * 1024 + t;
    int v = (i < n) ? data[i] : 0;
    int x = v;
    #pragma unroll
    for (int off = 1; off < 64; off <<= 1) {
        int y = __shfl_up(x, off);
        if (lane >= off) x += y;
    }
    if (lane == 63) wsum[w] = x;
    __syncthreads();
    if (t == 0) {
        int s = 0;
        #pragma unroll
        for (int q = 0; q < 16; ++q) { int tmp = wsum[q]; wsum[q] = s; s += tmp; }
        bsum[blockIdx.x] = s;
    }
    __syncthreads();
    if (i < n) data[i] = x - v + wsum[w];
}

__global__ __launch_bounds__(1024) void scan_sums_kernel(int* bsum, int nb)
{
    __shared__ int wsum[16];
    int t = threadIdx.x, lane = t & 63, w = t >> 6;
    int v = (t < nb) ? bsum[t] : 0;
    int x = v;
    #pragma unroll
    for (int off = 1; off < 64; off <<= 1) {
        int y = __shfl_up(x, off);
        if (lane >= off) x += y;
    }
    if (lane == 63) wsum[w] = x;
    __syncthreads();
    if (t == 0) {
        int s = 0;
        #pragma unroll
        for (int q = 0; q < 16; ++q) { int tmp = wsum[q]; wsum[q] = s; s += tmp; }
        bsum[nb] = s;                      // total
    }
    __syncthreads();
    if (t < nb) bsum[t] = x - v + wsum[w];
}

__global__ __launch_bounds__(256) void scan_add_kernel(
    int* __restrict__ data, const int* __restrict__ bsum, int n, int nb)
{
    int i = blockIdx.x * 256 + threadIdx.x;
    if (i < n) data[i] += bsum[i >> 10];
    if (i == 0) data[n] = bsum[nb];
}

// XCD-partitioned id scatter
__global__ __launch_bounds__(256) void scatter_part_kernel(
    const int* __restrict__ src, const int* __restrict__ dst,
    int* __restrict__ cursor, int* __restrict__ esrc,
    int n_edges, int npr, int nchunks)
{
    int r = blockIdx.x & 7;
    int c = blockIdx.x >> 3;
    int lo = r * npr, hi = lo + npr;
    int per = (n_edges + nchunks - 1) / nchunks;
    int e0 = c * per;
    int e1 = e0 + per; if (e1 > n_edges) e1 = n_edges;
    for (int e = e0 + (int)threadIdx.x; e < e1; e += 256) {
        int d = dst[e];
        if (d >= lo && d < hi) {
            int pos = atomicAdd(&cursor[d], 1);
            esrc[pos] = src[e];
        }
    }
}

// ---------------------------------------------------------------------------
// fp32 -> bf16 convert with scale
// ---------------------------------------------------------------------------
__global__ __launch_bounds__(256) void f2bf_kernel(
    const float* __restrict__ W, ushort* __restrict__ Wbf, float scale, int n)
{
    int i = blockIdx.x * 256 + threadIdx.x;
    if (i < n) Wbf[i] = f2bf(W[i] * scale);
}

// ---------------------------------------------------------------------------
// Fused gather-aggregate (CSR, bf16 rows) + self-loop + 64x64 sigmoid MLP.
// (R14-proven version)
// ---------------------------------------------------------------------------
__global__ __launch_bounds__(256) void agg_mlp_kernel(
    const ushort* __restrict__ hbf, const int* __restrict__ offsets,
    const int* __restrict__ esrc, const float* __restrict__ Hw,
    const float* __restrict__ Hb, ushort* __restrict__ outbf, int n_nodes)
{
    __shared__ float Hw_s[AF * 65];
    __shared__ __align__(16) float part[4][8][AF];   // 8 KB
    __shared__ float a_red[4][AF];
    __shared__ float hb_s[AF];

    int t = threadIdx.x;
    for (int idx = t; idx < AF * AF; idx += 256) {
        int j = idx >> 6, k = idx & 63;
        Hw_s[j * 65 + k] = Hw[idx];
    }
    if (t < AF) hb_s[t] = Hb[t];

    int w = t >> 6, lane = t & 63;
    int sub = lane >> 3, f8 = lane & 7;
    int i = blockIdx.x * 4 + w;

    float acc[8] = {0.f, 0.f, 0.f, 0.f, 0.f, 0.f, 0.f, 0.f};
    if (i < n_nodes) {
        int o0 = offsets[i], o1 = offsets[i + 1];
        const int* ep = esrc + o0;
        int deg = o1 - o0;
        for (int j = 0; j < deg; j += 8) {
            int jj = j + sub;
            if (jj < deg) {
                int s = ep[jj];
                bf16x8 v = *(const bf16x8*)(hbf + (size_t)s * AF + f8 * 8);
                #pragma unroll
                for (int q = 0; q < 8; ++q) acc[q] += bf2f((ushort)v[q]);
            }
        }
    }
    *(float4*)&part[w][sub][f8 * 8]     = make_float4(acc[0], acc[1], acc[2], acc[3]);
    *(float4*)&part[w][sub][f8 * 8 + 4] = make_float4(acc[4], acc[5], acc[6], acc[7]);
    __syncthreads();

    if (i < n_nodes) {
        float val = bf2f(hbf[(size_t)i * AF + lane]);   // self loop
        #pragma unroll
        for (int s8 = 0; s8 < 8; ++s8) val += part[w][s8][lane];
        a_red[w][lane] = val;
    }
    __syncthreads();

    if (i < n_nodes) {
        float z = hb_s[lane];
        #pragma unroll
        for (int k = 0; k < AF; ++k)
            z = fmaf(a_red[w][k], Hw_s[lane * 65 + k], z);
        float sg = 1.f / (1.f + __expf(-z));
        outbf[(size_t)i * AF + lane] = f2bf(sg);
    }
}

// ---------------------------------------------------------------------------
// FUSED fingerprint (R14-proven structure + LDS bias table): 256 thr = 4
// waves; 32 nodes/block; wave owns 512 cols (32 cts).  Bias (Wb*log2e)
// staged once in LDS -> per-ct bias becomes a conflict-free ds_read instead
// of an L2 VMEM load on the dependent chain.  Pass 1: GEMM + exp2 -> denoms.
// Pass 2: recompute tiles, per-graph masked pooling into wave-local pacc,
// plain-store partial[b+g]; reduce kernel sums rows.
// ---------------------------------------------------------------------------
__global__ __launch_bounds__(256) void fp_node_pool_kernel(
    const ushort* __restrict__ updbf, const ushort* __restrict__ Wbf,
    const float* __restrict__ Wb, const int* __restrict__ batch,
    float* __restrict__ partial, float* __restrict__ out, int n_nodes)
{
    __shared__ float red[4][32];
    __shared__ float sden_s[32];
    __shared__ int   bat_s[32];
    __shared__ float wb_s[NFP];                       // 8 KB, pre-scaled bias
    __shared__ __align__(16) float pacc[MAXG][NFP];   // 24 KB

    int t = threadIdx.x, wave = t >> 6, lane = t & 63;
    int G = lane >> 4, sl = lane & 15;
    int cw = wave * 512;
    int b = blockIdx.x;
    int i0 = b * 32;

    // stage bias*log2e into LDS (needs barrier before pass 1)
    #pragma unroll
    for (int j = 0; j < NFP / 256; ++j)
        wb_s[j * 256 + t] = Wb[j * 256 + t] * LOG2E;
    if (t < 32) {
        int n = i0 + t;
        bat_s[t] = batch[n < n_nodes ? n : (n_nodes - 1)];
    }

    // A fragments (updbf padded + zeroed past n_nodes)
    bf16x8 a00, a01, a10, a11;
    {
        const ushort* p0 = updbf + (size_t)(i0 + sl) * AF + G * 8;
        a00 = *(const bf16x8*)p0;
        a01 = *(const bf16x8*)(p0 + 32);
        const ushort* p1 = updbf + (size_t)(i0 + 16 + sl) * AF + G * 8;
        a10 = *(const bf16x8*)p1;
        a11 = *(const bf16x8*)(p1 + 32);
    }
    __syncthreads();   // wb_s / bat_s ready

    // ---- pass 1: denominators via exp2 (weights pre-scaled by log2e) ----
    float s0[4] = {0.f, 0.f, 0.f, 0.f};
    float s1[4] = {0.f, 0.f, 0.f, 0.f};
    {
        const ushort* wp0 = Wbf + (size_t)(cw + sl) * AF + G * 8;
        bf16x8 nb0 = *(const bf16x8*)wp0;
        bf16x8 nb1 = *(const bf16x8*)(wp0 + 32);
        #pragma unroll 4
        for (int ct = 0; ct < 32; ++ct) {
            bf16x8 b0 = nb0, b1 = nb1;
            if (ct < 31) {
                const ushort* wp = Wbf + (size_t)(cw + (ct + 1) * 16 + sl) * AF + G * 8;
                nb0 = *(const bf16x8*)wp;
                nb1 = *(const bf16x8*)(wp + 32);
            }
            float bias = wb_s[cw + ct * 16 + sl];
            f32x4 d0 = {0.f, 0.f, 0.f, 0.f};
            d0 = __builtin_amdgcn_mfma_f32_16x16x32_bf16(a00, b0, d0, 0, 0, 0);
            d0 = __builtin_amdgcn_mfma_f32_16x16x32_bf16(a01, b1, d0, 0, 0, 0);
            f32x4 d1 = {0.f, 0.f, 0.f, 0.f};
            d1 = __builtin_amdgcn_mfma_f32_16x16x32_bf16(a10, b0, d1, 0, 0, 0);
            d1 = __builtin_amdgcn_mfma_f32_16x16x32_bf16(a11, b1, d1, 0, 0, 0);
            #pragma unroll
            for (int r = 0; r < 4; ++r) {
                s0[r] += __builtin_amdgcn_exp2f(d0[r] + bias);
                s1[r] += __builtin_amdgcn_exp2f(d1[r] + bias);
            }
        }
    }
    #pragma unroll
    for (int mask = 1; mask <= 8; mask <<= 1) {
        #pragma unroll
        for (int r = 0; r < 4; ++r) {
            s0[r] += __shfl_xor(s0[r], mask);
            s1[r] += __shfl_xor(s1[r], mask);
        }
    }
    if (sl == 0) {
        #pragma unroll
        for (int r = 0; r < 4; ++r) {
            red[wave][G * 4 + r]      = s0[r];
            red[wave][16 + G * 4 + r] = s1[r];
        }
    }
    __syncthreads();
    if (t < 32) {
        float s = red[0][t] + red[1][t] + red[2][t] + red[3][t];
        sden_s[t] = 1.f / s;
    }
    __syncthreads();

    int g_first = bat_s[0];
    int ng = bat_s[31] - g_first + 1;            // block-uniform
    int ngl = ng < MAXG ? ng : MAXG;

    // zero wave-local pacc slices (wave-exclusive: no barrier needed)
    for (int gi = 0; gi < ngl; ++gi) {
        *(float4*)&pacc[gi][cw + lane * 8]     = make_float4(0.f, 0.f, 0.f, 0.f);
        *(float4*)&pacc[gi][cw + lane * 8 + 4] = make_float4(0.f, 0.f, 0.f, 0.f);
    }

    // per-lane scales & graph ids
    float sc0[4], sc1[4];
    int gl0[4], gl1[4];
    #pragma unroll
    for (int r = 0; r < 4; ++r) {
        int l0 = G * 4 + r, l1 = l0 + 16;
        sc0[r] = (i0 + l0 < n_nodes) ? sden_s[l0] : 0.f;
        sc1[r] = (i0 + l1 < n_nodes) ? sden_s[l1] : 0.f;
        gl0[r] = bat_s[l0];
        gl1[r] = bat_s[l1];
    }

    // ---- pass 2: recompute tiles, masked pool ----
    {
        const ushort* wp0 = Wbf + (size_t)(cw + sl) * AF + G * 8;
        bf16x8 nb0 = *(const bf16x8*)wp0;
        bf16x8 nb1 = *(const bf16x8*)(wp0 + 32);
        #pragma unroll 4
        for (int ct = 0; ct < 32; ++ct) {
            bf16x8 b0 = nb0, b1 = nb1;
            if (ct < 31) {
                const ushort* wp = Wbf + (size_t)(cw + (ct + 1) * 16 + sl) * AF + G * 8;
                nb0 = *(const bf16x8*)wp;
                nb1 = *(const bf16x8*)(wp + 32);
            }
            int col = cw + ct * 16 + sl;
            float bias = wb_s[col];
            f32x4 d0 = {0.f, 0.f, 0.f, 0.f};
            d0 = __builtin_amdgcn_mfma_f32_16x16x32_bf16(a00, b0, d0, 0, 0, 0);
            d0 = __builtin_amdgcn_mfma_f32_16x16x32_bf16(a01, b1, d0, 0, 0, 0);
            f32x4 d1 = {0.f, 0.f, 0.f, 0.f};
            d1 = __builtin_amdgcn_mfma_f32_16x16x32_bf16(a10, b0, d1, 0, 0, 0);
            d1 = __builtin_amdgcn_mfma_f32_16x16x32_bf16(a11, b1, d1, 0, 0, 0);
            float e0[4], e1[4];
            #pragma unroll
            for (int r = 0; r < 4; ++r) {
                e0[r] = __builtin_amdgcn_exp2f(d0[r] + bias) * sc0[r];
                e1[r] = __builtin_amdgcn_exp2f(d1[r] + bias) * sc1[r];
            }
            for (int gi = 0; gi < ng; ++gi) {       // block-uniform bound
                int g = g_first + gi;
                float c = 0.f;
                #pragma unroll
                for (int r = 0; r < 4; ++r) {
                    c += (gl0[r] == g) ? e0[r] : 0.f;
                    c += (gl1[r] == g) ? e1[r] : 0.f;
                }
                c += __shfl_xor(c, 16);
                c += __shfl_xor(c, 32);
                if (gi < MAXG) {
                    if (G == 0) pacc[gi][col] += c;   // wave-local col
                } else if (G == 0) {                  // pathological fallback
                    unsafeAtomicAdd(&out[(size_t)g * NFP + col], c);
                }
            }
        }
    }

    // epilogue: plain-store partial rows (row = b + g, injective)
    for (int gi = 0; gi < ng; ++gi) {
        float* row = partial + (size_t)(b + g_first + gi) * NFP;
        if (gi < MAXG) {
            *(float4*)&row[cw + lane * 8]     = *(float4*)&pacc[gi][cw + lane * 8];
            *(float4*)&row[cw + lane * 8 + 4] = *(float4*)&pacc[gi][cw + lane * 8 + 4];
        } else {
            *(float4*)&row[cw + lane * 8]     = make_float4(0.f, 0.f, 0.f, 0.f);
            *(float4*)&row[cw + lane * 8 + 4] = make_float4(0.f, 0.f, 0.f, 0.f);
        }
    }
}

// ---------------------------------------------------------------------------
// Per-graph reduce: out[g] += sum over covering 32-node blocks of partial[b+g].
// ---------------------------------------------------------------------------
__global__ __launch_bounds__(256) void fp_reduce_kernel(
    const float* __restrict__ partial, const int* __restrict__ goff,
    float* __restrict__ out)
{
    int g = blockIdx.x, t = threadIdx.x;
    int gs = goff[g], ge = goff[g + 1];
    if (ge <= gs) return;
    int b0 = gs >> 5, b1 = (ge - 1) >> 5;
    float4 acc0 = make_float4(0.f, 0.f, 0.f, 0.f);
    float4 acc1 = make_float4(0.f, 0.f, 0.f, 0.f);
    for (int b = b0; b <= b1; ++b) {
        const float* row = partial + (size_t)(b + g) * NFP;
        float4 v0 = *(const float4*)&row[t * 8];
        float4 v1 = *(const float4*)&row[t * 8 + 4];
        acc0.x += v0.x; acc0.y += v0.y; acc0.z += v0.z; acc0.w += v0.w;
        acc1.x += v1.x; acc1.y += v1.y; acc1.z += v1.z; acc1.w += v1.w;
    }
    float* po = &out[(size_t)g * NFP];
    float4 o0 = *(float4*)&po[t * 8];
    float4 o1 = *(float4*)&po[t * 8 + 4];
    o0.x += acc0.x; o0.y += acc0.y; o0.z += acc0.z; o0.w += acc0.w;
    o1.x += acc1.x; o1.y += acc1.y; o1.z += acc1.z; o1.w += acc1.w;
    *(float4*)&po[t * 8]     = o0;
    *(float4*)&po[t * 8 + 4] = o1;
}

// ---------------------------------------------------------------------------
extern "C" void kernel_launch(void* const* d_in, const int* in_sizes, int n_in,
                              void* d_out, int out_size, void* d_ws, size_t ws_size,
                              hipStream_t stream)
{
    const float* x    = (const float*)d_in[0];
    const float* H1_w = (const float*)d_in[1];
    const float* H1_b = (const float*)d_in[2];
    const float* W1_w = (const float*)d_in[3];
    const float* W1_b = (const float*)d_in[4];
    const float* H2_w = (const float*)d_in[5];
    const float* H2_b = (const float*)d_in[6];
    const float* W2_w = (const float*)d_in[7];
    const float* W2_b = (const float*)d_in[8];
    const int*   ei   = (const int*)d_in[9];
    const int*   batch= (const int*)d_in[10];

    const int n_nodes  = in_sizes[0] / AF;   // 50000
    const int n_edges  = in_sizes[9] / 2;    // 1600000
    const int n_graphs = out_size / NFP;     // 2000
    const int npad     = ((n_nodes + 127) / 128) * 128;   // 50048
    const int* src = ei;
    const int* dst = ei + n_edges;
    float* out = (float*)d_out;

    const int fp_blocks = (n_nodes + 31) / 32;            // 1563
    const int npairs    = fp_blocks + n_graphs + 1;       // partial rows
    const int nsb       = (n_nodes + 1023) / 1024;        // scan blocks (49)

    // workspace layout
    ushort* xbf     = (ushort*)d_ws;                     // npad*64
    ushort* ubf1    = xbf  + (size_t)npad * AF;          // npad*64
    ushort* ubf2    = ubf1 + (size_t)npad * AF;          // npad*64
    ushort* Wbf1    = ubf2 + (size_t)npad * AF;          // 131072
    ushort* Wbf2    = Wbf1 + (size_t)NFP * AF;           // 131072
    float*  partial = (float*)(Wbf2 + (size_t)NFP * AF); // npairs*NFP
    int*    offsets = (int*)(partial + (size_t)npairs * NFP);  // n_nodes+1
    int*    cursor  = offsets + (n_nodes + 1);           // n_nodes+1
    int*    goff    = cursor + (n_nodes + 1);            // n_graphs+1
    int*    bscan   = goff + (n_graphs + 1);             // nsb+1
    int*    esrc    = bscan + (nsb + 1);                 // n_edges

    const int nb = (n_nodes + 255) / 256;
    const int mlp_blocks = (n_nodes + 3) / 4;
    const int wn = NFP * AF;                 // 131072
    const int xn = n_nodes * AF;             // 3.2M
    const int npr = (n_nodes + 7) / 8;       // nodes per XCD-range
    const int nchunks = 256;                 // edge chunks per range sweep

    // --- one-time per launch: bf16 tables + CSR + graph offsets + pads ---
    f2bf_kernel<<<(xn + 255) / 256, 256, 0, stream>>>(x, xbf, 1.0f, xn);
    f2bf_kernel<<<(wn + 255) / 256, 256, 0, stream>>>(W1_w, Wbf1, LOG2E, wn);
    f2bf_kernel<<<(wn + 255) / 256, 256, 0, stream>>>(W2_w, Wbf2, LOG2E, wn);
    hipMemsetAsync(out, 0, (size_t)out_size * sizeof(float), stream);
    hipMemsetAsync(xbf + (size_t)n_nodes * AF, 0,
                   (size_t)(npad - n_nodes) * AF * sizeof(ushort), stream);
    hipMemsetAsync(ubf1 + (size_t)n_nodes * AF, 0,
                   (size_t)(npad - n_nodes) * AF * sizeof(ushort), stream);
    hipMemsetAsync(ubf2 + (size_t)n_nodes * AF, 0,
                   (size_t)(npad - n_nodes) * AF * sizeof(ushort), stream);
    hipMemsetAsync(offsets, 0, (size_t)(n_nodes + 1) * sizeof(int), stream);
    hipMemsetAsync(goff, 0, (size_t)(n_graphs + 1) * sizeof(int), stream);
    hist_part_kernel<<<nchunks * 8, 256, 0, stream>>>(dst, offsets, n_edges, npr, nchunks);
    hist_kernel<<<nb, 256, 0, stream>>>(batch, goff, n_nodes);
    scan_block_kernel<<<nsb, 1024, 0, stream>>>(offsets, bscan, n_nodes);
    scan_sums_kernel<<<1, 1024, 0, stream>>>(bscan, nsb);
    scan_add_kernel<<<(n_nodes + 255) / 256, 256, 0, stream>>>(offsets, bscan,
                                                               n_nodes, nsb);
    scan_kernel<<<1, 1024, 0, stream>>>(goff, n_graphs);
    hipMemcpyAsync(cursor, offsets, (size_t)n_nodes * sizeof(int),
                   hipMemcpyDeviceToDevice, stream);
    scatter_part_kernel<<<nchunks * 8, 256, 0, stream>>>(src, dst, cursor, esrc,
                                                         n_edges, npr, nchunks);

    // --- layer 1 ---
    agg_mlp_kernel<<<mlp_blocks, 256, 0, stream>>>(xbf, offsets, esrc,
                                                   H1_w, H1_b, ubf1, n_nodes);
    fp_node_pool_kernel<<<fp_blocks, 256, 0, stream>>>(ubf1, Wbf1, W1_b, batch,
                                                       partial, out, n_nodes);
    fp_reduce_kernel<<<n_graphs, 256, 0, stream>>>(partial, goff, out);

    // --- layer 2 ---
    agg_mlp_kernel<<<mlp_blocks, 256, 0, stream>>>(ubf1, offsets, esrc,
                                                   H2_w, H2_b, ubf2, n_nodes);
    fp_node_pool_kernel<<<fp_blocks, 256, 0, stream>>>(ubf2, Wbf2, W2_b, batch,
                                                       partial, out, n_nodes);
    fp_reduce_kernel<<<n_graphs, 256, 0, stream>>>(partial, goff, out);
}

// Round 18
// 586.466 us; speedup vs baseline: 2.7124x; 1.0150x over previous
//
#include <hip/hip_runtime.h>
#include <hip/hip_bf16.h>

// N_NODES=50000, N_EDGES=1600000, ATOM_F=64, FP_SIZE=2048, N_GRAPHS=2000
#define AF 64
#define NFP 2048
#define MAXG 3   // LDS-pooled graphs per 16-node block (fallback: global atomics)
#define LOG2E 1.4426950408889634f

typedef __attribute__((ext_vector_type(8))) short bf16x8;
typedef __attribute__((ext_vector_type(4))) float f32x4;

__device__ __forceinline__ ushort f2bf(float f) {
    unsigned u = __float_as_uint(f);
    return (ushort)((u + 0x7FFF + ((u >> 16) & 1)) >> 16);   // RNE
}
__device__ __forceinline__ float bf2f(ushort u) {
    return __uint_as_float((unsigned)u << 16);
}

// ---------------------------------------------------------------------------
// Generic histogram (int32 keys)
// ---------------------------------------------------------------------------
__global__ __launch_bounds__(256) void hist_kernel(
    const int* __restrict__ keys, int* __restrict__ counts, int n)
{
    int e = blockIdx.x * 256 + threadIdx.x;
    if (e < n) atomicAdd(&counts[keys[e]], 1);
}

// XCD-partitioned histogram
__global__ __launch_bounds__(256) void hist_part_kernel(
    const int* __restrict__ dst, int* __restrict__ counts,
    int n_edges, int npr, int nchunks)
{
    int r = blockIdx.x & 7;
    int c = blockIdx.x >> 3;
    int lo = r * npr, hi = lo + npr;
    int per = (n_edges + nchunks - 1) / nchunks;
    int e0 = c * per;
    int e1 = e0 + per; if (e1 > n_edges) e1 = n_edges;
    for (int e = e0 + (int)threadIdx.x; e < e1; e += 256) {
        int d = dst[e];
        if (d >= lo && d < hi) atomicAdd(&counts[d], 1);
    }
}

// single-block exclusive scan, in place; data[n] = total  (small arrays only)
__global__ __launch_bounds__(1024) void scan_kernel(int* data, int n)
{
    __shared__ int wsum[16];
    __shared__ int chunk_total;
    int t = threadIdx.x, lane = t & 63, w = t >> 6;
    int running = 0;
    for (int base = 0; base < n; base += 1024) {
        int i = base + t;
        int v = (i < n) ? data[i] : 0;
        int x = v;
        #pragma unroll
        for (int off = 1; off < 64; off <<= 1) {
            int y = __shfl_up(x, off);
            if (lane >= off) x += y;
        }
        if (lane == 63) wsum[w] = x;
        __syncthreads();
        if (t == 0) {
            int s = 0;
            #pragma unroll
            for (int q = 0; q < 16; ++q) { int tmp = wsum[q]; wsum[q] = s; s += tmp; }
            chunk_total = s;
        }
        __syncthreads();
        if (i < n) data[i] = x - v + wsum[w] + running;
        running += chunk_total;
        __syncthreads();
    }
    if (t == 0) data[n] = running;
}

// --- hierarchical scan for large arrays: block scan + sums scan + add ---
__global__ __launch_bounds__(1024) void scan_block_kernel(
    int* __restrict__ data, int* __restrict__ bsum, int n)
{
    __shared__ int wsum[16];
    int t = threadIdx.x, lane = t & 63, w = t >> 6;
    int i = blockIdx.x * 1024 + t;
    int v = (i < n) ? data[i] : 0;
    int x = v;
    #pragma unroll
    for (int off = 1; off < 64; off <<= 1) {
        int y = __shfl_up(x, off);
        if (lane >= off) x += y;
    }
    if (lane == 63) wsum[w] = x;
    __syncthreads();
    if (t == 0) {
        int s = 0;
        #pragma unroll
        for (int q = 0; q < 16; ++q) { int tmp = wsum[q]; wsum[q] = s; s += tmp; }
        bsum[blockIdx.x] = s;
    }
    __syncthreads();
    if (i < n) data[i] = x - v + wsum[w];
}

__global__ __launch_bounds__(1024) void scan_sums_kernel(int* bsum, int nb)
{
    __shared__ int wsum[16];
    int t = threadIdx.x, lane = t & 63, w = t >> 6;
    int v = (t < nb) ? bsum[t] : 0;
    int x = v;
    #pragma unroll
    for (int off = 1; off < 64; off <<= 1) {
        int y = __shfl_up(x, off);
        if (lane >= off) x += y;
    }
    if (lane == 63) wsum[w] = x;
    __syncthreads();
    if (t == 0) {
        int s = 0;
        #pragma unroll
        for (int q = 0; q < 16; ++q) { int tmp = wsum[q]; wsum[q] = s; s += tmp; }
        bsum[nb] = s;                      // total
    }
    __syncthreads();
    if (t < nb) bsum[t] = x - v + wsum[w];
}

__global__ __launch_bounds__(256) void scan_add_kernel(
    int* __restrict__ data, const int* __restrict__ bsum, int n, int nb)
{
    int i = blockIdx.x * 256 + threadIdx.x;
    if (i < n) data[i] += bsum[i >> 10];
    if (i == 0) data[n] = bsum[nb];
}

// XCD-partitioned id scatter
__global__ __launch_bounds__(256) void scatter_part_kernel(
    const int* __restrict__ src, const int* __restrict__ dst,
    int* __restrict__ cursor, int* __restrict__ esrc,
    int n_edges, int npr, int nchunks)
{
    int r = blockIdx.x & 7;
    int c = blockIdx.x >> 3;
    int lo = r * npr, hi = lo + npr;
    int per = (n_edges + nchunks - 1) / nchunks;
    int e0 = c * per;
    int e1 = e0 + per; if (e1 > n_edges) e1 = n_edges;
    for (int e = e0 + (int)threadIdx.x; e < e1; e += 256) {
        int d = dst[e];
        if (d >= lo && d < hi) {
            int pos = atomicAdd(&cursor[d], 1);
            esrc[pos] = src[e];
        }
    }
}

// ---------------------------------------------------------------------------
// fp32 -> bf16 convert with scale
// ---------------------------------------------------------------------------
__global__ __launch_bounds__(256) void f2bf_kernel(
    const float* __restrict__ W, ushort* __restrict__ Wbf, float scale, int n)
{
    int i = blockIdx.x * 256 + threadIdx.x;
    if (i < n) Wbf[i] = f2bf(W[i] * scale);
}

// ---------------------------------------------------------------------------
// Fused gather-aggregate (CSR, bf16 rows) + self-loop + 64x64 sigmoid MLP.
// ---------------------------------------------------------------------------
__global__ __launch_bounds__(256) void agg_mlp_kernel(
    const ushort* __restrict__ hbf, const int* __restrict__ offsets,
    const int* __restrict__ esrc, const float* __restrict__ Hw,
    const float* __restrict__ Hb, ushort* __restrict__ outbf, int n_nodes)
{
    __shared__ float Hw_s[AF * 65];
    __shared__ __align__(16) float part[4][8][AF];   // 8 KB
    __shared__ float a_red[4][AF];
    __shared__ float hb_s[AF];

    int t = threadIdx.x;
    for (int idx = t; idx < AF * AF; idx += 256) {
        int j = idx >> 6, k = idx & 63;
        Hw_s[j * 65 + k] = Hw[idx];
    }
    if (t < AF) hb_s[t] = Hb[t];

    int w = t >> 6, lane = t & 63;
    int sub = lane >> 3, f8 = lane & 7;
    int i = blockIdx.x * 4 + w;

    float acc[8] = {0.f, 0.f, 0.f, 0.f, 0.f, 0.f, 0.f, 0.f};
    if (i < n_nodes) {
        int o0 = offsets[i], o1 = offsets[i + 1];
        const int* ep = esrc + o0;
        int deg = o1 - o0;
        for (int j = 0; j < deg; j += 8) {
            int jj = j + sub;
            if (jj < deg) {
                int s = ep[jj];
                bf16x8 v = *(const bf16x8*)(hbf + (size_t)s * AF + f8 * 8);
                #pragma unroll
                for (int q = 0; q < 8; ++q) acc[q] += bf2f((ushort)v[q]);
            }
        }
    }
    *(float4*)&part[w][sub][f8 * 8]     = make_float4(acc[0], acc[1], acc[2], acc[3]);
    *(float4*)&part[w][sub][f8 * 8 + 4] = make_float4(acc[4], acc[5], acc[6], acc[7]);
    __syncthreads();

    if (i < n_nodes) {
        float val = bf2f(hbf[(size_t)i * AF + lane]);   // self loop
        #pragma unroll
        for (int s8 = 0; s8 < 8; ++s8) val += part[w][s8][lane];
        a_red[w][lane] = val;
    }
    __syncthreads();

    if (i < n_nodes) {
        float z = hb_s[lane];
        #pragma unroll
        for (int k = 0; k < AF; ++k)
            z = fmaf(a_red[w][k], Hw_s[lane * 65 + k], z);
        float sg = 1.f / (1.f + __expf(-z));
        outbf[(size_t)i * AF + lane] = f2bf(sg);
    }
}

// ---------------------------------------------------------------------------
// FUSED fingerprint, SINGLE GEMM + SINGLE exp, e cached in fp32 registers.
// 512 thr = 8 waves; 16 nodes/block (one MFMA row-tile); wave owns 256 cols
// (16 cts, fully unrolled, branch-free -> ef[16][4] stays in 64 VGPRs).
// Pass 1: GEMM + exp2 (LDS bias table), accumulate denom, cache e.
// Denom reduce; pre-scale ef by sden.
// Pool: gi OUTER (runtime), ct INNER (static unroll) — rule-#20-compliant;
// MAXG branch hoisted outside the unrolled loop.  partial[b+g] staircase
// (strictly increasing -> injective) + per-graph reduce, as proven.
// ---------------------------------------------------------------------------
__global__ __launch_bounds__(512) void fp_node_pool_kernel(
    const ushort* __restrict__ updbf, const ushort* __restrict__ Wbf,
    const float* __restrict__ Wb, const int* __restrict__ batch,
    float* __restrict__ partial, float* __restrict__ out, int n_nodes)
{
    __shared__ float red[8][16];
    __shared__ float sden_s[16];
    __shared__ int   bat_s[16];
    __shared__ float wb_s[NFP];                       // 8 KB, pre-scaled bias
    __shared__ __align__(16) float pacc[MAXG][NFP];   // 24 KB

    int t = threadIdx.x, wave = t >> 6, lane = t & 63;
    int G = lane >> 4, sl = lane & 15;
    int cw = wave * 256;
    int b = blockIdx.x;
    int i0 = b * 16;

    // stage bias*log2e into LDS; batch window
    #pragma unroll
    for (int j = 0; j < NFP / 512; ++j)
        wb_s[j * 512 + t] = Wb[j * 512 + t] * LOG2E;
    if (t < 16) {
        int n = i0 + t;
        bat_s[t] = batch[n < n_nodes ? n : (n_nodes - 1)];
    }

    // A fragments (updbf padded + zeroed past n_nodes)
    bf16x8 a0, a1;
    {
        const ushort* p0 = updbf + (size_t)(i0 + sl) * AF + G * 8;
        a0 = *(const bf16x8*)p0;
        a1 = *(const bf16x8*)(p0 + 32);
    }
    __syncthreads();   // wb_s / bat_s ready

    // ---- pass 1: GEMM + exp2, cache e in regs, accumulate denom ----
    float s0[4] = {0.f, 0.f, 0.f, 0.f};
    float ef[16][4];
    {
        const ushort* wp0 = Wbf + (size_t)(cw + sl) * AF + G * 8;
        bf16x8 nb0 = *(const bf16x8*)wp0;
        bf16x8 nb1 = *(const bf16x8*)(wp0 + 32);
        #pragma unroll
        for (int ct = 0; ct < 16; ++ct) {
            bf16x8 b0 = nb0, b1 = nb1;
            if (ct < 15) {
                const ushort* wp = Wbf + (size_t)(cw + (ct + 1) * 16 + sl) * AF + G * 8;
                nb0 = *(const bf16x8*)wp;
                nb1 = *(const bf16x8*)(wp + 32);
            }
            float bias = wb_s[cw + ct * 16 + sl];
            f32x4 d = {0.f, 0.f, 0.f, 0.f};
            d = __builtin_amdgcn_mfma_f32_16x16x32_bf16(a0, b0, d, 0, 0, 0);
            d = __builtin_amdgcn_mfma_f32_16x16x32_bf16(a1, b1, d, 0, 0, 0);
            #pragma unroll
            for (int r = 0; r < 4; ++r) {
                float e = __builtin_amdgcn_exp2f(d[r] + bias);
                ef[ct][r] = e;
                s0[r] += e;
            }
        }
    }
    // denom reduce: 16-lane group, then cross-wave via LDS
    #pragma unroll
    for (int mask = 1; mask <= 8; mask <<= 1) {
        #pragma unroll
        for (int r = 0; r < 4; ++r) s0[r] += __shfl_xor(s0[r], mask);
    }
    if (sl == 0) {
        #pragma unroll
        for (int r = 0; r < 4; ++r) red[wave][G * 4 + r] = s0[r];
    }
    __syncthreads();
    if (t < 16) {
        float s = 0.f;
        #pragma unroll
        for (int w8 = 0; w8 < 8; ++w8) s += red[w8][t];
        sden_s[t] = 1.f / s;
    }
    __syncthreads();

    int g_first = bat_s[0];
    int ng = bat_s[15] - g_first + 1;            // block-uniform
    int ngl = ng < MAXG ? ng : MAXG;

    // zero wave-local pacc col-slices (wave-exclusive, no barrier needed)
    for (int gi = 0; gi < ngl; ++gi)
        *(float4*)&pacc[gi][cw + lane * 4] = make_float4(0.f, 0.f, 0.f, 0.f);

    // per-lane scales & graph ids; pre-scale ef by sden (once)
    float sc0[4];
    int gl0[4];
    #pragma unroll
    for (int r = 0; r < 4; ++r) {
        int l0 = G * 4 + r;
        sc0[r] = (i0 + l0 < n_nodes) ? sden_s[l0] : 0.f;
        gl0[r] = bat_s[l0];
    }
    #pragma unroll
    for (int ct = 0; ct < 16; ++ct) {
        #pragma unroll
        for (int r = 0; r < 4; ++r) ef[ct][r] *= sc0[r];
    }

    // ---- pool: gi outer (runtime), ct inner (static unroll) ----
    for (int gi = 0; gi < ng; ++gi) {
        int g = g_first + gi;
        if (gi < MAXG) {
            #pragma unroll
            for (int ct = 0; ct < 16; ++ct) {
                int col = cw + ct * 16 + sl;
                float c = ((gl0[0] == g) ? ef[ct][0] : 0.f)
                        + ((gl0[1] == g) ? ef[ct][1] : 0.f)
                        + ((gl0[2] == g) ? ef[ct][2] : 0.f)
                        + ((gl0[3] == g) ? ef[ct][3] : 0.f);
                c += __shfl_xor(c, 16);
                c += __shfl_xor(c, 32);
                if (G == 0) pacc[gi][col] += c;   // wave-local col
            }
        } else {                                  // pathological fallback
            #pragma unroll
            for (int ct = 0; ct < 16; ++ct) {
                int col = cw + ct * 16 + sl;
                float c = ((gl0[0] == g) ? ef[ct][0] : 0.f)
                        + ((gl0[1] == g) ? ef[ct][1] : 0.f)
                        + ((gl0[2] == g) ? ef[ct][2] : 0.f)
                        + ((gl0[3] == g) ? ef[ct][3] : 0.f);
                c += __shfl_xor(c, 16);
                c += __shfl_xor(c, 32);
                if (G == 0)
                    unsafeAtomicAdd(&out[(size_t)g * NFP + col], c);
            }
        }
    }

    // epilogue: plain-store partial rows (row = b + g, strictly increasing)
    for (int gi = 0; gi < ng; ++gi) {
        float* row = partial + (size_t)(b + g_first + gi) * NFP;
        float4 v = make_float4(0.f, 0.f, 0.f, 0.f);
        if (gi < MAXG) v = *(float4*)&pacc[gi][cw + lane * 4];
        *(float4*)&row[cw + lane * 4] = v;
    }
}

// ---------------------------------------------------------------------------
// Per-graph reduce: out[g] += sum over covering 16-node blocks of partial[b+g].
// ---------------------------------------------------------------------------
__global__ __launch_bounds__(256) void fp_reduce_kernel(
    const float* __restrict__ partial, const int* __restrict__ goff,
    float* __restrict__ out)
{
    int g = blockIdx.x, t = threadIdx.x;
    int gs = goff[g], ge = goff[g + 1];
    if (ge <= gs) return;
    int b0 = gs >> 4, b1 = (ge - 1) >> 4;
    float4 acc0 = make_float4(0.f, 0.f, 0.f, 0.f);
    float4 acc1 = make_float4(0.f, 0.f, 0.f, 0.f);
    for (int b = b0; b <= b1; ++b) {
        const float* row = partial + (size_t)(b + g) * NFP;
        float4 v0 = *(const float4*)&row[t * 8];
        float4 v1 = *(const float4*)&row[t * 8 + 4];
        acc0.x += v0.x; acc0.y += v0.y; acc0.z += v0.z; acc0.w += v0.w;
        acc1.x += v1.x; acc1.y += v1.y; acc1.z += v1.z; acc1.w += v1.w;
    }
    float* po = &out[(size_t)g * NFP];
    float4 o0 = *(float4*)&po[t * 8];
    float4 o1 = *(float4*)&po[t * 8 + 4];
    o0.x += acc0.x; o0.y += acc0.y; o0.z += acc0.z; o0.w += acc0.w;
    o1.x += acc1.x; o1.y += acc1.y; o1.z += acc1.z; o1.w += acc1.w;
    *(float4*)&po[t * 8]     = o0;
    *(float4*)&po[t * 8 + 4] = o1;
}

// ---------------------------------------------------------------------------
extern "C" void kernel_launch(void* const* d_in, const int* in_sizes, int n_in,
                              void* d_out, int out_size, void* d_ws, size_t ws_size,
                              hipStream_t stream)
{
    const float* x    = (const float*)d_in[0];
    const float* H1_w = (const float*)d_in[1];
    const float* H1_b = (const float*)d_in[2];
    const float* W1_w = (const float*)d_in[3];
    const float* W1_b = (const float*)d_in[4];
    const float* H2_w = (const float*)d_in[5];
    const float* H2_b = (const float*)d_in[6];
    const float* W2_w = (const float*)d_in[7];
    const float* W2_b = (const float*)d_in[8];
    const int*   ei   = (const int*)d_in[9];
    const int*   batch= (const int*)d_in[10];

    const int n_nodes  = in_sizes[0] / AF;   // 50000
    const int n_edges  = in_sizes[9] / 2;    // 1600000
    const int n_graphs = out_size / NFP;     // 2000
    const int npad     = ((n_nodes + 127) / 128) * 128;   // 50048
    const int* src = ei;
    const int* dst = ei + n_edges;
    float* out = (float*)d_out;

    const int fp_blocks = (n_nodes + 15) / 16;            // 3125
    const int npairs    = fp_blocks + n_graphs + 1;       // partial rows
    const int nsb       = (n_nodes + 1023) / 1024;        // scan blocks (49)

    // workspace layout
    ushort* xbf     = (ushort*)d_ws;                     // npad*64
    ushort* ubf1    = xbf  + (size_t)npad * AF;          // npad*64
    ushort* ubf2    = ubf1 + (size_t)npad * AF;          // npad*64
    ushort* Wbf1    = ubf2 + (size_t)npad * AF;          // 131072
    ushort* Wbf2    = Wbf1 + (size_t)NFP * AF;           // 131072
    float*  partial = (float*)(Wbf2 + (size_t)NFP * AF); // npairs*NFP
    int*    offsets = (int*)(partial + (size_t)npairs * NFP);  // n_nodes+1
    int*    cursor  = offsets + (n_nodes + 1);           // n_nodes+1
    int*    goff    = cursor + (n_nodes + 1);            // n_graphs+1
    int*    bscan   = goff + (n_graphs + 1);             // nsb+1
    int*    esrc    = bscan + (nsb + 1);                 // n_edges

    const int nb = (n_nodes + 255) / 256;
    const int mlp_blocks = (n_nodes + 3) / 4;
    const int wn = NFP * AF;                 // 131072
    const int xn = n_nodes * AF;             // 3.2M
    const int npr = (n_nodes + 7) / 8;       // nodes per XCD-range
    const int nchunks = 256;                 // edge chunks per range sweep

    // --- one-time per launch: bf16 tables + CSR + graph offsets + pads ---
    f2bf_kernel<<<(xn + 255) / 256, 256, 0, stream>>>(x, xbf, 1.0f, xn);
    f2bf_kernel<<<(wn + 255) / 256, 256, 0, stream>>>(W1_w, Wbf1, LOG2E, wn);
    f2bf_kernel<<<(wn + 255) / 256, 256, 0, stream>>>(W2_w, Wbf2, LOG2E, wn);
    hipMemsetAsync(out, 0, (size_t)out_size * sizeof(float), stream);
    hipMemsetAsync(xbf + (size_t)n_nodes * AF, 0,
                   (size_t)(npad - n_nodes) * AF * sizeof(ushort), stream);
    hipMemsetAsync(ubf1 + (size_t)n_nodes * AF, 0,
                   (size_t)(npad - n_nodes) * AF * sizeof(ushort), stream);
    hipMemsetAsync(ubf2 + (size_t)n_nodes * AF, 0,
                   (size_t)(npad - n_nodes) * AF * sizeof(ushort), stream);
    hipMemsetAsync(offsets, 0, (size_t)(n_nodes + 1) * sizeof(int), stream);
    hipMemsetAsync(goff, 0, (size_t)(n_graphs + 1) * sizeof(int), stream);
    hist_part_kernel<<<nchunks * 8, 256, 0, stream>>>(dst, offsets, n_edges, npr, nchunks);
    hist_kernel<<<nb, 256, 0, stream>>>(batch, goff, n_nodes);
    scan_block_kernel<<<nsb, 1024, 0, stream>>>(offsets, bscan, n_nodes);
    scan_sums_kernel<<<1, 1024, 0, stream>>>(bscan, nsb);
    scan_add_kernel<<<(n_nodes + 255) / 256, 256, 0, stream>>>(offsets, bscan,
                                                               n_nodes, nsb);
    scan_kernel<<<1, 1024, 0, stream>>>(goff, n_graphs);
    hipMemcpyAsync(cursor, offsets, (size_t)n_nodes * sizeof(int),
                   hipMemcpyDeviceToDevice, stream);
    scatter_part_kernel<<<nchunks * 8, 256, 0, stream>>>(src, dst, cursor, esrc,
                                                         n_edges, npr, nchunks);

    // --- layer 1 ---
    agg_mlp_kernel<<<mlp_blocks, 256, 0, stream>>>(xbf, offsets, esrc,
                                                   H1_w, H1_b, ubf1, n_nodes);
    fp_node_pool_kernel<<<fp_blocks, 512, 0, stream>>>(ubf1, Wbf1, W1_b, batch,
                                                       partial, out, n_nodes);
    fp_reduce_kernel<<<n_graphs, 256, 0, stream>>>(partial, goff, out);

    // --- layer 2 ---
    agg_mlp_kernel<<<mlp_blocks, 256, 0, stream>>>(ubf1, offsets, esrc,
                                                   H2_w, H2_b, ubf2, n_nodes);
    fp_node_pool_kernel<<<fp_blocks, 512, 0, stream>>>(ubf2, Wbf2, W2_b, batch,
                                                       partial, out, n_nodes);
    fp_reduce_kernel<<<n_graphs, 256, 0, stream>>>(partial, goff, out);
}